// Round 3
// baseline (350.610 us; speedup 1.0000x reference)
//
#include <hip/hip_runtime.h>
#include <math.h>

#define B_   16
#define L_   256
#define V_   50000
#define NV_  50100
#define E_   128
#define H_   128
#define G4_  512
#define CHUNK_ 1566   // ceil(50100/32)

typedef float f32x4 __attribute__((ext_vector_type(4)));
typedef float f32x2 __attribute__((ext_vector_type(2)));

__device__ __forceinline__ float sigm(float x){ return 1.0f/(1.0f+__expf(-x)); }
__device__ __forceinline__ float tanh_fast(float x){
  x = fminf(15.0f, fmaxf(-15.0f, x));
  float t = __expf(2.0f*x);
  return (t-1.0f)/(t+1.0f);
}

// ---------------- K1: encoder xg = emb[tok] @ W_ih^T + b ----------------
// 128 blocks x 512 threads, 16 token rows per block
__global__ __launch_bounds__(512) void enc_xg_kernel(
    const int* __restrict__ tok, const float* __restrict__ emb,
    const float* __restrict__ Wih, const float* __restrict__ bias,
    float* __restrict__ xg)
{
  __shared__ __align__(16) float sx[16*128];
  int r0 = blockIdx.x*16;
  int t = threadIdx.x;
  for (int i=t; i<16*128; i+=512){
    int r=i>>7, e=i&127;
    sx[i] = emb[(size_t)tok[r0+r]*E_ + e];
  }
  __syncthreads();
  int g = t;
  float acc[16];
  #pragma unroll
  for (int r=0;r<16;r++) acc[r]=0.f;
  const f32x4* wr = (const f32x4*)(Wih + (size_t)g*E_);
  #pragma unroll 2
  for (int i=0;i<32;i++){
    f32x4 w = wr[i];
    #pragma unroll
    for (int r=0;r<16;r++){
      f32x4 x = ((const f32x4*)(sx + r*128))[i];
      acc[r] += w.x*x.x + w.y*x.y + w.z*x.z + w.w*x.w;
    }
  }
  float bg = bias[g];
  #pragma unroll
  for (int r=0;r<16;r++) xg[(size_t)(r0+r)*G4_ + g] = acc[r] + bg;
}

// ---------------- K2: encoder LSTM recurrence ----------------
// 16 blocks (one per batch), 512 threads (one gate each).
// waves_per_eu(2,2): exactly 1 block/CU -> 256 VGPR budget.
// asm keepalive makes w2 non-rematerializable so RA must keep 128 VGPRs of
// W_hh resident (R1/R2: compiler sank the loads -> 256KB/step from L2 ->
// ~1900cy/step, the measured bottleneck).
__global__ void __attribute__((amdgpu_flat_work_group_size(512,512), amdgpu_waves_per_eu(2,2)))
enc_lstm_kernel(
    const float* __restrict__ xg, const float* __restrict__ Whh,
    float* __restrict__ enc_out)
{
  int b = blockIdx.x;
  int g = threadIdx.x;
  f32x2 w2[64];
  {
    const f32x4* wr4 = (const f32x4*)(Whh + (size_t)g*H_);
    #pragma unroll
    for (int k=0;k<32;k++){
      f32x4 wv = wr4[k];
      w2[2*k]   = wv.xy;
      w2[2*k+1] = wv.zw;
    }
  }
  #pragma unroll
  for (int k=0;k<64;k++) asm volatile("" : "+v"(w2[k]));

  __shared__ __align__(16) float sh_h[128];
  __shared__ float sh_g[512];
  if (g<128) sh_h[g]=0.f;
  float c = 0.f;
  const float* xgb = xg + (size_t)b*L_*G4_;
  float* eob = enc_out + (size_t)b*L_*H_;
  __syncthreads();

  const f32x4* sh4 = (const f32x4*)sh_h;
  bool is_gg = (g>=256 && g<384);   // tanh gate (wave-uniform)
  float xcur = xgb[g];
  for (int t=0;t<L_;t++){
    float xnext = (t<L_-1) ? xgb[(t+1)*G4_ + g] : 0.f;  // prefetch
    f32x2 a0 = {xcur, 0.f}, a1 = {0.f,0.f}, a2 = {0.f,0.f}, a3 = {0.f,0.f};
    #pragma unroll
    for (int k=0;k<32;k+=4){
      f32x4 h0=sh4[k], h1=sh4[k+1], h2v=sh4[k+2], h3=sh4[k+3];
      a0 += w2[2*k+0]*h0.xy;  a1 += w2[2*k+1]*h0.zw;
      a2 += w2[2*k+2]*h1.xy;  a3 += w2[2*k+3]*h1.zw;
      a0 += w2[2*k+4]*h2v.xy; a1 += w2[2*k+5]*h2v.zw;
      a2 += w2[2*k+6]*h3.xy;  a3 += w2[2*k+7]*h3.zw;
    }
    f32x2 as = (a0+a1)+(a2+a3);
    float acc = as.x + as.y;
    float act = is_gg ? tanh_fast(acc) : sigm(acc);
    sh_g[g] = act;
    __syncthreads();
    if (g < 128){
      c = sh_g[128+g]*c + sh_g[g]*sh_g[256+g];
      float h = sh_g[384+g]*tanh_fast(c);
      sh_h[g] = h;
      eob[t*H_ + g] = h;
    }
    __syncthreads();
    xcur = xnext;
  }
}

// ---------------- fused middle: copy scores + copy softmax/state + dec step + attention ----------------
__global__ __launch_bounds__(512) void fuse_mid_kernel(
    const int* __restrict__ src, const int* __restrict__ prev,
    const float* __restrict__ enc_out, const float* __restrict__ cW,
    const float* __restrict__ dstate, const float* __restrict__ emb,
    const float* __restrict__ dWih, const float* __restrict__ db,
    const float* __restrict__ aW, const float* __restrict__ oW,
    const float* __restrict__ ob, float* __restrict__ attn_out)
{
  int b=blockIdx.x, t=threadIdx.x;
  __shared__ float s_scopy[256];
  __shared__ int   mlist[256];
  __shared__ int   mcnt;
  __shared__ __align__(16) float se[128];
  __shared__ float sw[256];
  __shared__ float spart[512];
  __shared__ float sred[4];
  __shared__ __align__(16) float sin_[256];
  __shared__ float sg[512];
  __shared__ __align__(16) float sr[128];
  __shared__ __align__(16) float sq[128];
  __shared__ float sc[256];
  __shared__ __align__(16) float sctx[128];

  // ---- A0: copy-attention raw scores (mask matches are rare) ----
  if (t==0) mcnt=0;
  __syncthreads();
  if (t<256){
    s_scopy[t]=0.f;
    if (src[b*L_+t]==prev[b]){ int i=atomicAdd(&mcnt,1); mlist[i]=t; }
  }
  __syncthreads();
  for (int mi=0; mi<mcnt; mi++){
    int l = mlist[mi];
    if (t<128) se[t] = enc_out[((size_t)b*L_+l)*H_ + t];
    __syncthreads();
    if (t<128){
      const f32x4* wr = (const f32x4*)(cW + (size_t)t*H_);
      const f32x4* e4 = (const f32x4*)se;
      float acc=0.f;
      #pragma unroll
      for (int i=0;i<32;i++){
        f32x4 wv=wr[i], e=e4[i];
        acc += wv.x*e.x + wv.y*e.y + wv.z*e.z + wv.w*e.w;
      }
      float v = tanhf(acc)*dstate[b*H_+t];
      #pragma unroll
      for (int o=32;o;o>>=1) v += __shfl_down(v,o);
      if ((t&63)==0) sred[t>>6]=v;
    }
    __syncthreads();
    if (t==0) s_scopy[l]=sred[0]+sred[1];
    __syncthreads();
  }

  // ---- A1: softmax over copy scores (t<256 active) ----
  float v = (t<256) ? s_scopy[t] : -INFINITY;
  {
    float m=v;
    #pragma unroll
    for (int o=32;o;o>>=1) m=fmaxf(m,__shfl_down(m,o));
    if (t<256 && (t&63)==0) sred[t>>6]=m;
  }
  __syncthreads();
  float m4 = fmaxf(fmaxf(sred[0],sred[1]),fmaxf(sred[2],sred[3]));
  __syncthreads();
  float e = (t<256) ? __expf(v-m4) : 0.f;
  {
    float z=e;
    #pragma unroll
    for (int o=32;o;o>>=1) z += __shfl_down(z,o);
    if (t<256 && (t&63)==0) sred[t>>6]=z;
  }
  __syncthreads();
  {
    float z4 = sred[0]+sred[1]+sred[2]+sred[3];
    if (t<256) sw[t] = e/z4;
  }
  __syncthreads();

  // ---- A2: copy_state = sum_l sw[l]*enc_out[b,l,:] ----
  {
    int ch=t>>7, h=t&127;
    float acc=0.f;
    const float* eb = enc_out + (size_t)b*L_*H_;
    for (int l=ch*64; l<ch*64+64; l++) acc += sw[l]*eb[(size_t)l*H_+h];
    spart[t]=acc;
  }
  __syncthreads();
  if (t<128){
    float cst = spart[t]+spart[128+t]+spart[256+t]+spart[384+t];
    sin_[128+t]=cst;
    sin_[t]=emb[(size_t)prev[b]*E_+t];
  }
  __syncthreads();

  // ---- B: decoder single LSTM step (h0=c0=0) ----
  {
    const f32x4* wr=(const f32x4*)(dWih + (size_t)t*256);
    const f32x4* x4=(const f32x4*)sin_;
    f32x2 d0={db[t],0.f}, d1={0.f,0.f}, d2={0.f,0.f}, d3={0.f,0.f};
    #pragma unroll
    for (int k=0;k<64;k+=4){
      f32x4 xa=x4[k], xb=x4[k+1], xc=x4[k+2], xd=x4[k+3];
      f32x4 wa=wr[k], wb=wr[k+1], wc=wr[k+2], wd=wr[k+3];
      d0 += wa.xy*xa.xy; d1 += wa.zw*xa.zw;
      d2 += wb.xy*xb.xy; d3 += wb.zw*xb.zw;
      d0 += wc.xy*xc.xy; d1 += wc.zw*xc.zw;
      d2 += wd.xy*xd.xy; d3 += wd.zw*xd.zw;
    }
    f32x2 dsm=(d0+d1)+(d2+d3);
    sg[t]=dsm.x+dsm.y;
  }
  __syncthreads();
  if (t<128){
    float iv=sg[t], gv=sg[256+t], ov=sg[384+t];   // f-gate * c0 = 0
    float cc = sigm(iv)*tanhf(gv);
    sr[t] = sigm(ov)*tanhf(cc);
  }
  __syncthreads();

  // ---- C1: q = attn_W @ rnn ----
  if (t<128){
    const f32x4* wr=(const f32x4*)(aW + (size_t)t*H_);
    const f32x4* x4=(const f32x4*)sr;
    float acc=0.f;
    #pragma unroll
    for (int i=0;i<32;i++){
      f32x4 wv=wr[i], x=x4[i];
      acc += wv.x*x.x + wv.y*x.y + wv.z*x.z + wv.w*x.w;
    }
    sq[t]=acc;
  }
  __syncthreads();

  // ---- C2: scores + pad mask ----
  if (t<256){
    const f32x4* e4=(const f32x4*)(enc_out + ((size_t)b*L_+t)*H_);
    const f32x4* q4=(const f32x4*)sq;
    float acc=0.f;
    #pragma unroll
    for (int i=0;i<32;i++){
      f32x4 ev=e4[i], q=q4[i];
      acc += ev.x*q.x + ev.y*q.y + ev.z*q.z + ev.w*q.w;
    }
    if (src[b*L_+t]==0) acc=-INFINITY;
    sc[t]=acc;
  }
  __syncthreads();

  // ---- attn softmax ----
  v = (t<256) ? sc[t] : -INFINITY;
  {
    float m=v;
    #pragma unroll
    for (int o=32;o;o>>=1) m=fmaxf(m,__shfl_down(m,o));
    if (t<256 && (t&63)==0) sred[t>>6]=m;
  }
  __syncthreads();
  m4 = fmaxf(fmaxf(sred[0],sred[1]),fmaxf(sred[2],sred[3]));
  __syncthreads();
  e = (t<256) ? __expf(v-m4) : 0.f;
  {
    float z=e;
    #pragma unroll
    for (int o=32;o;o>>=1) z += __shfl_down(z,o);
    if (t<256 && (t&63)==0) sred[t>>6]=z;
  }
  __syncthreads();
  {
    float z4 = sred[0]+sred[1]+sred[2]+sred[3];
    if (t<256) sc[t] = e/z4;
  }
  __syncthreads();

  // ---- C3: ctx ----
  {
    int ch=t>>7, h=t&127;
    float acc=0.f;
    const float* eb = enc_out + (size_t)b*L_*H_;
    for (int l=ch*64; l<ch*64+64; l++) acc += sc[l]*eb[(size_t)l*H_+h];
    spart[t]=acc;
  }
  __syncthreads();
  if (t<128) sctx[t] = spart[t]+spart[128+t]+spart[256+t]+spart[384+t];
  __syncthreads();

  // ---- C4: attn_out = tanh(out_W @ [rnn,ctx] + out_b) ----
  if (t<128){
    const f32x4* wr=(const f32x4*)(oW + (size_t)t*256);
    const f32x4* r4=(const f32x4*)sr;
    const f32x4* c4=(const f32x4*)sctx;
    float acc=ob[t];
    #pragma unroll
    for (int i=0;i<32;i++){
      f32x4 wv=wr[i], x=r4[i];
      acc += wv.x*x.x + wv.y*x.y + wv.z*x.z + wv.w*x.w;
    }
    #pragma unroll
    for (int i=0;i<32;i++){
      f32x4 wv=wr[32+i], x=c4[i];
      acc += wv.x*x.x + wv.y*x.y + wv.z*x.z + wv.w*x.w;
    }
    attn_out[b*H_+t]=tanhf(acc);
  }
}

// ---------------- K7a: first-occurrence aggregation of enc_out by token ----------------
__global__ __launch_bounds__(256) void copy_agg_kernel(
    const int* __restrict__ stw, const float* __restrict__ enc_out,
    float* __restrict__ agg, int* __restrict__ replist, int* __restrict__ repcnt)
{
  int b=blockIdx.x, l=threadIdx.x;
  __shared__ int stok[256];
  __shared__ int scnt;
  stok[l] = stw[b*L_+l];
  if (l==0) scnt=0;
  __syncthreads();
  int tok = stok[l];
  int first=0;
  while (stok[first]!=tok) first++;
  if (first==l){
    int myidx = atomicAdd(&scnt,1);
    f32x4 acc[32];
    #pragma unroll
    for (int i=0;i<32;i++) acc[i]=(f32x4){0.f,0.f,0.f,0.f};
    for (int l2=l; l2<L_; l2++){
      if (stok[l2]==tok){
        const f32x4* e=(const f32x4*)(enc_out + ((size_t)b*L_+l2)*H_);
        #pragma unroll
        for (int i=0;i<32;i++) acc[i]+=e[i];
      }
    }
    f32x4* dst=(f32x4*)(agg + ((size_t)b*L_+l)*H_);
    #pragma unroll
    for (int i=0;i<32;i++) dst[i]=acc[i];
    replist[b*L_+myidx]=l;
  }
  __syncthreads();
  if (l==0) repcnt[b]=scnt;
}

// ---------------- K9: gen logits + masks -> total ----------------
__global__ __launch_bounds__(256) void gen_logits_kernel(
    const float* __restrict__ attn_out, const float* __restrict__ gW,
    const int* __restrict__ oovc, float* __restrict__ total)
{
  __shared__ float sa[B_*H_];
  __shared__ float sw[64*129];
  int t=threadIdx.x;
  int v0=blockIdx.x*64;
  for (int i=t;i<B_*H_;i+=256) sa[i]=attn_out[i];
  for (int i=t;i<64*32;i+=256){
    int r=i>>5, cc=i&31;
    if (v0+r<NV_){
      float4 wv = ((const float4*)(gW + (size_t)(v0+r)*H_))[cc];
      float* dst = sw + r*129 + cc*4;
      dst[0]=wv.x; dst[1]=wv.y; dst[2]=wv.z; dst[3]=wv.w;
    }
  }
  __syncthreads();
  int vl=t&63, bq=t>>6;
  int v=v0+vl;
  if (v>=NV_) return;
  float acc[4]={0.f,0.f,0.f,0.f};
  const float* wrow = sw + vl*129;
  #pragma unroll 8
  for (int h4=0; h4<32; h4++){
    float w0=wrow[h4*4+0], w1=wrow[h4*4+1], w2=wrow[h4*4+2], w3=wrow[h4*4+3];
    #pragma unroll
    for (int k=0;k<4;k++){
      float4 a = ((const float4*)(sa + (bq*4+k)*H_))[h4];
      acc[k] += w0*a.x + w1*a.y + w2*a.z + w3*a.w;
    }
  }
  #pragma unroll
  for (int k=0;k<4;k++){
    int b=bq*4+k;
    float o = (v==1 || v >= V_ + oovc[b]) ? -INFINITY : acc[k];
    total[(size_t)b*NV_ + v] = o;
  }
}

// ---------------- K7b: sparse copy scores added into total ----------------
__global__ __launch_bounds__(128) void copy_score2_kernel(
    const int* __restrict__ stw, const float* __restrict__ agg,
    const float* __restrict__ cW, const float* __restrict__ attn_out,
    const int* __restrict__ replist, const int* __restrict__ repcnt,
    float* __restrict__ total)
{
  int b=blockIdx.x;
  int cnt=repcnt[b];
  int g=threadIdx.x;
  __shared__ __align__(16) float srow[128];
  __shared__ float sred[2];
  float aog = attn_out[b*H_+g];
  f32x4 w[32];
  const f32x4* wrow=(const f32x4*)(cW + (size_t)g*H_);
  #pragma unroll
  for (int i=0;i<32;i++) w[i]=wrow[i];
  for (int ri=blockIdx.y; ri<cnt; ri+=gridDim.y){
    int l = replist[b*L_+ri];
    srow[g] = agg[((size_t)b*L_+l)*H_+g];
    __syncthreads();
    float acc=0.f;
    #pragma unroll
    for (int i=0;i<32;i++){
      f32x4 e=((const f32x4*)srow)[i]; f32x4 wv=w[i];
      acc += wv.x*e.x + wv.y*e.y + wv.z*e.z + wv.w*e.w;
    }
    float v = tanhf(acc)*aog;
    #pragma unroll
    for (int o=32;o;o>>=1) v += __shfl_down(v,o);
    if ((g&63)==0) sred[g>>6]=v;
    __syncthreads();
    if (g==0){
      int vtok = stw[b*L_+l];
      total[(size_t)b*NV_ + vtok] += sred[0]+sred[1];
    }
    __syncthreads();
  }
}

// ---------------- K10: vocab softmax ----------------
// pass A: one block per row, full max+sum -> MZ
__global__ __launch_bounds__(1024) void vocab_reduce_kernel(
    const float* __restrict__ total, float* __restrict__ MZ)
{
  int b=blockIdx.x, t=threadIdx.x;
  const float* row = total + (size_t)b*NV_;
  __shared__ float sred[16];
  float m=-INFINITY;
  for (int i=t;i<NV_;i+=1024) m=fmaxf(m,row[i]);
  #pragma unroll
  for (int o=32;o;o>>=1) m=fmaxf(m,__shfl_down(m,o));
  if ((t&63)==0) sred[t>>6]=m;
  __syncthreads();
  if (t<64){
    float mm = (t<16) ? sred[t] : -INFINITY;
    #pragma unroll
    for (int o=8;o;o>>=1) mm=fmaxf(mm,__shfl_down(mm,o));
    if (t==0) sred[0]=mm;
  }
  __syncthreads();
  m = sred[0];
  float s=0.f;
  for (int i=t;i<NV_;i+=1024) s += __expf(row[i]-m);
  #pragma unroll
  for (int o=32;o;o>>=1) s += __shfl_down(s,o);
  __syncthreads();
  if ((t&63)==0) sred[t>>6]=s;
  __syncthreads();
  if (t<64){
    float ss = (t<16) ? sred[t] : 0.f;
    #pragma unroll
    for (int o=8;o;o>>=1) ss += __shfl_down(ss,o);
    if (t==0){ MZ[b]=m; MZ[16+b]=ss; }
  }
}

__global__ __launch_bounds__(256) void vocab_norm_kernel(
    float* __restrict__ total, const float* __restrict__ MZ)
{
  int b=blockIdx.x, j=blockIdx.y, t=threadIdx.x;
  int lo=j*CHUNK_, hi=min(lo+CHUNK_, NV_);
  float m=MZ[b], rz=1.0f/MZ[16+b];
  float* row = total + (size_t)b*NV_;
  for (int i=lo+t;i<hi;i+=256) row[i] = __expf(row[i]-m)*rz;
}

// ---------------- launch ----------------
extern "C" void kernel_launch(void* const* d_in, const int* in_sizes, int n_in,
                              void* d_out, int out_size, void* d_ws, size_t ws_size,
                              hipStream_t stream)
{
  const int*   src_tokens = (const int*)d_in[0];
  const int*   prev_tok   = (const int*)d_in[2];
  const int*   stw        = (const int*)d_in[4];
  const int*   oovc       = (const int*)d_in[5];
  const float* dstate     = (const float*)d_in[6];
  const float* emb        = (const float*)d_in[7];
  const float* enc_Wih    = (const float*)d_in[8];
  const float* enc_Whh    = (const float*)d_in[9];
  const float* enc_b      = (const float*)d_in[10];
  const float* dec_Wih    = (const float*)d_in[11];
  const float* dec_b      = (const float*)d_in[13];
  const float* attn_W     = (const float*)d_in[14];
  const float* out_W      = (const float*)d_in[15];
  const float* out_b      = (const float*)d_in[16];
  const float* copy_W     = (const float*)d_in[17];
  const float* gen_W      = (const float*)d_in[18];

  float* out      = (float*)d_out;
  float* total    = out;                                 // B*NV
  float* enc_out  = out + (size_t)B_*NV_;                // B*L*H
  float* attn_out = enc_out + (size_t)B_*L_*H_;          // B*H

  float* ws     = (float*)d_ws;
  float* xg     = ws;                                    // B*L*G4
  float* agg    = xg + (size_t)B_*L_*G4_;                // B*L*H
  float* MZ     = agg + (size_t)B_*L_*H_;                // 32
  int*   replist= (int*)(MZ + 32);                       // B*L
  int*   repcnt = replist + B_*L_;                       // 16

  enc_xg_kernel<<<B_*L_/16, 512, 0, stream>>>(src_tokens, emb, enc_Wih, enc_b, xg);
  enc_lstm_kernel<<<B_, 512, 0, stream>>>(xg, enc_Whh, enc_out);
  fuse_mid_kernel<<<B_, 512, 0, stream>>>(src_tokens, prev_tok, enc_out, copy_W, dstate,
                                          emb, dec_Wih, dec_b, attn_W, out_W, out_b, attn_out);
  copy_agg_kernel<<<B_, 256, 0, stream>>>(stw, enc_out, agg, replist, repcnt);
  gen_logits_kernel<<<(NV_+63)/64, 256, 0, stream>>>(attn_out, gen_W, oovc, total);
  copy_score2_kernel<<<dim3(B_,32), 128, 0, stream>>>(stw, agg, copy_W, attn_out, replist, repcnt, total);
  vocab_reduce_kernel<<<B_, 1024, 0, stream>>>(total, MZ);
  vocab_norm_kernel<<<dim3(B_,32), 256, 0, stream>>>(total, MZ);
}

// Round 4
// 350.088 us; speedup vs baseline: 1.0015x; 1.0015x over previous
//
#include <hip/hip_runtime.h>
#include <math.h>

#define B_   16
#define L_   256
#define V_   50000
#define NV_  50100
#define E_   128
#define H_   128
#define G4_  512
#define CHUNK_ 1566   // ceil(50100/32)

typedef float f32x4 __attribute__((ext_vector_type(4)));
typedef float f32x2 __attribute__((ext_vector_type(2)));

__device__ __forceinline__ float sigm(float x){ return 1.0f/(1.0f+__expf(-x)); }
__device__ __forceinline__ float tanh_fast(float x){
  x = fminf(15.0f, fmaxf(-15.0f, x));
  float t = __expf(2.0f*x);
  return (t-1.0f)/(t+1.0f);
}

// ---------------- K1: encoder xg = emb[tok] @ W_ih^T + b ----------------
// 128 blocks x 512 threads, 16 token rows per block
__global__ __launch_bounds__(512) void enc_xg_kernel(
    const int* __restrict__ tok, const float* __restrict__ emb,
    const float* __restrict__ Wih, const float* __restrict__ bias,
    float* __restrict__ xg)
{
  __shared__ __align__(16) float sx[16*128];
  int r0 = blockIdx.x*16;
  int t = threadIdx.x;
  for (int i=t; i<16*128; i+=512){
    int r=i>>7, e=i&127;
    sx[i] = emb[(size_t)tok[r0+r]*E_ + e];
  }
  __syncthreads();
  int g = t;
  float acc[16];
  #pragma unroll
  for (int r=0;r<16;r++) acc[r]=0.f;
  const f32x4* wr = (const f32x4*)(Wih + (size_t)g*E_);
  #pragma unroll 2
  for (int i=0;i<32;i++){
    f32x4 w = wr[i];
    #pragma unroll
    for (int r=0;r<16;r++){
      f32x4 x = ((const f32x4*)(sx + r*128))[i];
      acc[r] += w.x*x.x + w.y*x.y + w.z*x.z + w.w*x.w;
    }
  }
  float bg = bias[g];
  #pragma unroll
  for (int r=0;r<16;r++) xg[(size_t)(r0+r)*G4_ + g] = acc[r] + bg;
}

// ---------------- K2: encoder LSTM recurrence ----------------
// 16 blocks (one per batch), 512 threads (one gate each).
// __launch_bounds__(512,2): RA budget 256 VGPR (proven applied in R2 — no
// scratch spill there, only remat). asm keepalive: blocks remat (proven in
// R3 — values stayed live). Combined: pressure ~170 <= budget 256 -> W_hh
// row stays fully VGPR-resident, no per-step reload.
__global__ __launch_bounds__(512, 2) void enc_lstm_kernel(
    const float* __restrict__ xg, const float* __restrict__ Whh,
    float* __restrict__ enc_out)
{
  int b = blockIdx.x;
  int g = threadIdx.x;
  f32x2 w2[64];
  {
    const f32x4* wr4 = (const f32x4*)(Whh + (size_t)g*H_);
    #pragma unroll
    for (int k=0;k<32;k++){
      f32x4 wv = wr4[k];
      w2[2*k]   = wv.xy;
      w2[2*k+1] = wv.zw;
    }
  }
  #pragma unroll
  for (int k=0;k<64;k++) asm volatile("" : "+v"(w2[k]));

  __shared__ __align__(16) float sh_h[128];
  __shared__ float sh_g[512];
  if (g<128) sh_h[g]=0.f;
  float c = 0.f;
  const float* xgb = xg + (size_t)b*L_*G4_;
  float* eob = enc_out + (size_t)b*L_*H_;
  __syncthreads();

  const f32x4* sh4 = (const f32x4*)sh_h;
  bool is_gg = (g>=256 && g<384);   // tanh gate (wave-uniform)
  float xcur = xgb[g];
  for (int t=0;t<L_;t++){
    float xnext = (t<L_-1) ? xgb[(t+1)*G4_ + g] : 0.f;  // prefetch
    f32x2 a0 = {xcur, 0.f}, a1 = {0.f,0.f}, a2 = {0.f,0.f}, a3 = {0.f,0.f};
    #pragma unroll
    for (int k=0;k<32;k+=4){
      f32x4 h0=sh4[k], h1=sh4[k+1], h2v=sh4[k+2], h3=sh4[k+3];
      a0 += w2[2*k+0]*h0.xy;  a1 += w2[2*k+1]*h0.zw;
      a2 += w2[2*k+2]*h1.xy;  a3 += w2[2*k+3]*h1.zw;
      a0 += w2[2*k+4]*h2v.xy; a1 += w2[2*k+5]*h2v.zw;
      a2 += w2[2*k+6]*h3.xy;  a3 += w2[2*k+7]*h3.zw;
    }
    f32x2 as = (a0+a1)+(a2+a3);
    float acc = as.x + as.y;
    float act = is_gg ? tanh_fast(acc) : sigm(acc);
    sh_g[g] = act;
    __syncthreads();
    if (g < 128){
      c = sh_g[128+g]*c + sh_g[g]*sh_g[256+g];
      float h = sh_g[384+g]*tanh_fast(c);
      sh_h[g] = h;
      eob[t*H_ + g] = h;
    }
    __syncthreads();
    xcur = xnext;
  }
}

// ---------------- fused middle: copy scores + copy softmax/state + dec step + attention ----------------
__global__ __launch_bounds__(512) void fuse_mid_kernel(
    const int* __restrict__ src, const int* __restrict__ prev,
    const float* __restrict__ enc_out, const float* __restrict__ cW,
    const float* __restrict__ dstate, const float* __restrict__ emb,
    const float* __restrict__ dWih, const float* __restrict__ db,
    const float* __restrict__ aW, const float* __restrict__ oW,
    const float* __restrict__ ob, float* __restrict__ attn_out)
{
  int b=blockIdx.x, t=threadIdx.x;
  __shared__ float s_scopy[256];
  __shared__ int   mlist[256];
  __shared__ int   mcnt;
  __shared__ __align__(16) float se[128];
  __shared__ float sw[256];
  __shared__ float spart[512];
  __shared__ float sred[4];
  __shared__ __align__(16) float sin_[256];
  __shared__ float sg[512];
  __shared__ __align__(16) float sr[128];
  __shared__ __align__(16) float sq[128];
  __shared__ float sc[256];
  __shared__ __align__(16) float sctx[128];

  // ---- A0: copy-attention raw scores (mask matches are rare) ----
  if (t==0) mcnt=0;
  __syncthreads();
  if (t<256){
    s_scopy[t]=0.f;
    if (src[b*L_+t]==prev[b]){ int i=atomicAdd(&mcnt,1); mlist[i]=t; }
  }
  __syncthreads();
  for (int mi=0; mi<mcnt; mi++){
    int l = mlist[mi];
    if (t<128) se[t] = enc_out[((size_t)b*L_+l)*H_ + t];
    __syncthreads();
    if (t<128){
      const f32x4* wr = (const f32x4*)(cW + (size_t)t*H_);
      const f32x4* e4 = (const f32x4*)se;
      float acc=0.f;
      #pragma unroll
      for (int i=0;i<32;i++){
        f32x4 wv=wr[i], e=e4[i];
        acc += wv.x*e.x + wv.y*e.y + wv.z*e.z + wv.w*e.w;
      }
      float v = tanhf(acc)*dstate[b*H_+t];
      #pragma unroll
      for (int o=32;o;o>>=1) v += __shfl_down(v,o);
      if ((t&63)==0) sred[t>>6]=v;
    }
    __syncthreads();
    if (t==0) s_scopy[l]=sred[0]+sred[1];
    __syncthreads();
  }

  // ---- A1: softmax over copy scores (t<256 active) ----
  float v = (t<256) ? s_scopy[t] : -INFINITY;
  {
    float m=v;
    #pragma unroll
    for (int o=32;o;o>>=1) m=fmaxf(m,__shfl_down(m,o));
    if (t<256 && (t&63)==0) sred[t>>6]=m;
  }
  __syncthreads();
  float m4 = fmaxf(fmaxf(sred[0],sred[1]),fmaxf(sred[2],sred[3]));
  __syncthreads();
  float e = (t<256) ? __expf(v-m4) : 0.f;
  {
    float z=e;
    #pragma unroll
    for (int o=32;o;o>>=1) z += __shfl_down(z,o);
    if (t<256 && (t&63)==0) sred[t>>6]=z;
  }
  __syncthreads();
  {
    float z4 = sred[0]+sred[1]+sred[2]+sred[3];
    if (t<256) sw[t] = e/z4;
  }
  __syncthreads();

  // ---- A2: copy_state = sum_l sw[l]*enc_out[b,l,:] ----
  {
    int ch=t>>7, h=t&127;
    float acc=0.f;
    const float* eb = enc_out + (size_t)b*L_*H_;
    for (int l=ch*64; l<ch*64+64; l++) acc += sw[l]*eb[(size_t)l*H_+h];
    spart[t]=acc;
  }
  __syncthreads();
  if (t<128){
    float cst = spart[t]+spart[128+t]+spart[256+t]+spart[384+t];
    sin_[128+t]=cst;
    sin_[t]=emb[(size_t)prev[b]*E_+t];
  }
  __syncthreads();

  // ---- B: decoder single LSTM step (h0=c0=0) ----
  {
    const f32x4* wr=(const f32x4*)(dWih + (size_t)t*256);
    const f32x4* x4=(const f32x4*)sin_;
    f32x2 d0={db[t],0.f}, d1={0.f,0.f}, d2={0.f,0.f}, d3={0.f,0.f};
    #pragma unroll
    for (int k=0;k<64;k+=4){
      f32x4 xa=x4[k], xb=x4[k+1], xc=x4[k+2], xd=x4[k+3];
      f32x4 wa=wr[k], wb=wr[k+1], wc=wr[k+2], wd=wr[k+3];
      d0 += wa.xy*xa.xy; d1 += wa.zw*xa.zw;
      d2 += wb.xy*xb.xy; d3 += wb.zw*xb.zw;
      d0 += wc.xy*xc.xy; d1 += wc.zw*xc.zw;
      d2 += wd.xy*xd.xy; d3 += wd.zw*xd.zw;
    }
    f32x2 dsm=(d0+d1)+(d2+d3);
    sg[t]=dsm.x+dsm.y;
  }
  __syncthreads();
  if (t<128){
    float iv=sg[t], gv=sg[256+t], ov=sg[384+t];   // f-gate * c0 = 0
    float cc = sigm(iv)*tanhf(gv);
    sr[t] = sigm(ov)*tanhf(cc);
  }
  __syncthreads();

  // ---- C1: q = attn_W @ rnn ----
  if (t<128){
    const f32x4* wr=(const f32x4*)(aW + (size_t)t*H_);
    const f32x4* x4=(const f32x4*)sr;
    float acc=0.f;
    #pragma unroll
    for (int i=0;i<32;i++){
      f32x4 wv=wr[i], x=x4[i];
      acc += wv.x*x.x + wv.y*x.y + wv.z*x.z + wv.w*x.w;
    }
    sq[t]=acc;
  }
  __syncthreads();

  // ---- C2: scores + pad mask ----
  if (t<256){
    const f32x4* e4=(const f32x4*)(enc_out + ((size_t)b*L_+t)*H_);
    const f32x4* q4=(const f32x4*)sq;
    float acc=0.f;
    #pragma unroll
    for (int i=0;i<32;i++){
      f32x4 ev=e4[i], q=q4[i];
      acc += ev.x*q.x + ev.y*q.y + ev.z*q.z + ev.w*q.w;
    }
    if (src[b*L_+t]==0) acc=-INFINITY;
    sc[t]=acc;
  }
  __syncthreads();

  // ---- attn softmax ----
  v = (t<256) ? sc[t] : -INFINITY;
  {
    float m=v;
    #pragma unroll
    for (int o=32;o;o>>=1) m=fmaxf(m,__shfl_down(m,o));
    if (t<256 && (t&63)==0) sred[t>>6]=m;
  }
  __syncthreads();
  m4 = fmaxf(fmaxf(sred[0],sred[1]),fmaxf(sred[2],sred[3]));
  __syncthreads();
  e = (t<256) ? __expf(v-m4) : 0.f;
  {
    float z=e;
    #pragma unroll
    for (int o=32;o;o>>=1) z += __shfl_down(z,o);
    if (t<256 && (t&63)==0) sred[t>>6]=z;
  }
  __syncthreads();
  {
    float z4 = sred[0]+sred[1]+sred[2]+sred[3];
    if (t<256) sc[t] = e/z4;
  }
  __syncthreads();

  // ---- C3: ctx ----
  {
    int ch=t>>7, h=t&127;
    float acc=0.f;
    const float* eb = enc_out + (size_t)b*L_*H_;
    for (int l=ch*64; l<ch*64+64; l++) acc += sc[l]*eb[(size_t)l*H_+h];
    spart[t]=acc;
  }
  __syncthreads();
  if (t<128) sctx[t] = spart[t]+spart[128+t]+spart[256+t]+spart[384+t];
  __syncthreads();

  // ---- C4: attn_out = tanh(out_W @ [rnn,ctx] + out_b) ----
  if (t<128){
    const f32x4* wr=(const f32x4*)(oW + (size_t)t*256);
    const f32x4* r4=(const f32x4*)sr;
    const f32x4* c4=(const f32x4*)sctx;
    float acc=ob[t];
    #pragma unroll
    for (int i=0;i<32;i++){
      f32x4 wv=wr[i], x=r4[i];
      acc += wv.x*x.x + wv.y*x.y + wv.z*x.z + wv.w*x.w;
    }
    #pragma unroll
    for (int i=0;i<32;i++){
      f32x4 wv=wr[32+i], x=c4[i];
      acc += wv.x*x.x + wv.y*x.y + wv.z*x.z + wv.w*x.w;
    }
    attn_out[b*H_+t]=tanhf(acc);
  }
}

// ---------------- K7a: first-occurrence aggregation of enc_out by token ----------------
__global__ __launch_bounds__(256) void copy_agg_kernel(
    const int* __restrict__ stw, const float* __restrict__ enc_out,
    float* __restrict__ agg, int* __restrict__ replist, int* __restrict__ repcnt)
{
  int b=blockIdx.x, l=threadIdx.x;
  __shared__ int stok[256];
  __shared__ int scnt;
  stok[l] = stw[b*L_+l];
  if (l==0) scnt=0;
  __syncthreads();
  int tok = stok[l];
  int first=0;
  while (stok[first]!=tok) first++;
  if (first==l){
    int myidx = atomicAdd(&scnt,1);
    f32x4 acc[32];
    #pragma unroll
    for (int i=0;i<32;i++) acc[i]=(f32x4){0.f,0.f,0.f,0.f};
    for (int l2=l; l2<L_; l2++){
      if (stok[l2]==tok){
        const f32x4* e=(const f32x4*)(enc_out + ((size_t)b*L_+l2)*H_);
        #pragma unroll
        for (int i=0;i<32;i++) acc[i]+=e[i];
      }
    }
    f32x4* dst=(f32x4*)(agg + ((size_t)b*L_+l)*H_);
    #pragma unroll
    for (int i=0;i<32;i++) dst[i]=acc[i];
    replist[b*L_+myidx]=l;
  }
  __syncthreads();
  if (l==0) repcnt[b]=scnt;
}

// ---------------- K9: gen logits + masks -> total ----------------
__global__ __launch_bounds__(256) void gen_logits_kernel(
    const float* __restrict__ attn_out, const float* __restrict__ gW,
    const int* __restrict__ oovc, float* __restrict__ total)
{
  __shared__ float sa[B_*H_];
  __shared__ float sw[64*129];
  int t=threadIdx.x;
  int v0=blockIdx.x*64;
  for (int i=t;i<B_*H_;i+=256) sa[i]=attn_out[i];
  for (int i=t;i<64*32;i+=256){
    int r=i>>5, cc=i&31;
    if (v0+r<NV_){
      float4 wv = ((const float4*)(gW + (size_t)(v0+r)*H_))[cc];
      float* dst = sw + r*129 + cc*4;
      dst[0]=wv.x; dst[1]=wv.y; dst[2]=wv.z; dst[3]=wv.w;
    }
  }
  __syncthreads();
  int vl=t&63, bq=t>>6;
  int v=v0+vl;
  if (v>=NV_) return;
  float acc[4]={0.f,0.f,0.f,0.f};
  const float* wrow = sw + vl*129;
  #pragma unroll 8
  for (int h4=0; h4<32; h4++){
    float w0=wrow[h4*4+0], w1=wrow[h4*4+1], w2=wrow[h4*4+2], w3=wrow[h4*4+3];
    #pragma unroll
    for (int k=0;k<4;k++){
      float4 a = ((const float4*)(sa + (bq*4+k)*H_))[h4];
      acc[k] += w0*a.x + w1*a.y + w2*a.z + w3*a.w;
    }
  }
  #pragma unroll
  for (int k=0;k<4;k++){
    int b=bq*4+k;
    float o = (v==1 || v >= V_ + oovc[b]) ? -INFINITY : acc[k];
    total[(size_t)b*NV_ + v] = o;
  }
}

// ---------------- K7b: sparse copy scores added into total ----------------
__global__ __launch_bounds__(128) void copy_score2_kernel(
    const int* __restrict__ stw, const float* __restrict__ agg,
    const float* __restrict__ cW, const float* __restrict__ attn_out,
    const int* __restrict__ replist, const int* __restrict__ repcnt,
    float* __restrict__ total)
{
  int b=blockIdx.x;
  int cnt=repcnt[b];
  int g=threadIdx.x;
  __shared__ __align__(16) float srow[128];
  __shared__ float sred[2];
  float aog = attn_out[b*H_+g];
  f32x4 w[32];
  const f32x4* wrow=(const f32x4*)(cW + (size_t)g*H_);
  #pragma unroll
  for (int i=0;i<32;i++) w[i]=wrow[i];
  for (int ri=blockIdx.y; ri<cnt; ri+=gridDim.y){
    int l = replist[b*L_+ri];
    srow[g] = agg[((size_t)b*L_+l)*H_+g];
    __syncthreads();
    float acc=0.f;
    #pragma unroll
    for (int i=0;i<32;i++){
      f32x4 e=((const f32x4*)srow)[i]; f32x4 wv=w[i];
      acc += wv.x*e.x + wv.y*e.y + wv.z*e.z + wv.w*e.w;
    }
    float v = tanhf(acc)*aog;
    #pragma unroll
    for (int o=32;o;o>>=1) v += __shfl_down(v,o);
    if ((g&63)==0) sred[g>>6]=v;
    __syncthreads();
    if (g==0){
      int vtok = stw[b*L_+l];
      total[(size_t)b*NV_ + vtok] += sred[0]+sred[1];
    }
    __syncthreads();
  }
}

// ---------------- K10: vocab softmax ----------------
__global__ __launch_bounds__(1024) void vocab_reduce_kernel(
    const float* __restrict__ total, float* __restrict__ MZ)
{
  int b=blockIdx.x, t=threadIdx.x;
  const float* row = total + (size_t)b*NV_;
  __shared__ float sred[16];
  float m=-INFINITY;
  for (int i=t;i<NV_;i+=1024) m=fmaxf(m,row[i]);
  #pragma unroll
  for (int o=32;o;o>>=1) m=fmaxf(m,__shfl_down(m,o));
  if ((t&63)==0) sred[t>>6]=m;
  __syncthreads();
  if (t<64){
    float mm = (t<16) ? sred[t] : -INFINITY;
    #pragma unroll
    for (int o=8;o;o>>=1) mm=fmaxf(mm,__shfl_down(mm,o));
    if (t==0) sred[0]=mm;
  }
  __syncthreads();
  m = sred[0];
  float s=0.f;
  for (int i=t;i<NV_;i+=1024) s += __expf(row[i]-m);
  #pragma unroll
  for (int o=32;o;o>>=1) s += __shfl_down(s,o);
  __syncthreads();
  if ((t&63)==0) sred[t>>6]=s;
  __syncthreads();
  if (t<64){
    float ss = (t<16) ? sred[t] : 0.f;
    #pragma unroll
    for (int o=8;o;o>>=1) ss += __shfl_down(ss,o);
    if (t==0){ MZ[b]=m; MZ[16+b]=ss; }
  }
}

__global__ __launch_bounds__(256) void vocab_norm_kernel(
    float* __restrict__ total, const float* __restrict__ MZ)
{
  int b=blockIdx.x, j=blockIdx.y, t=threadIdx.x;
  int lo=j*CHUNK_, hi=min(lo+CHUNK_, NV_);
  float m=MZ[b], rz=1.0f/MZ[16+b];
  float* row = total + (size_t)b*NV_;
  for (int i=lo+t;i<hi;i+=256) row[i] = __expf(row[i]-m)*rz;
}

// ---------------- launch ----------------
extern "C" void kernel_launch(void* const* d_in, const int* in_sizes, int n_in,
                              void* d_out, int out_size, void* d_ws, size_t ws_size,
                              hipStream_t stream)
{
  const int*   src_tokens = (const int*)d_in[0];
  const int*   prev_tok   = (const int*)d_in[2];
  const int*   stw        = (const int*)d_in[4];
  const int*   oovc       = (const int*)d_in[5];
  const float* dstate     = (const float*)d_in[6];
  const float* emb        = (const float*)d_in[7];
  const float* enc_Wih    = (const float*)d_in[8];
  const float* enc_Whh    = (const float*)d_in[9];
  const float* enc_b      = (const float*)d_in[10];
  const float* dec_Wih    = (const float*)d_in[11];
  const float* dec_b      = (const float*)d_in[13];
  const float* attn_W     = (const float*)d_in[14];
  const float* out_W      = (const float*)d_in[15];
  const float* out_b      = (const float*)d_in[16];
  const float* copy_W     = (const float*)d_in[17];
  const float* gen_W      = (const float*)d_in[18];

  float* out      = (float*)d_out;
  float* total    = out;                                 // B*NV
  float* enc_out  = out + (size_t)B_*NV_;                // B*L*H
  float* attn_out = enc_out + (size_t)B_*L_*H_;          // B*H

  float* ws     = (float*)d_ws;
  float* xg     = ws;                                    // B*L*G4
  float* agg    = xg + (size_t)B_*L_*G4_;                // B*L*H
  float* MZ     = agg + (size_t)B_*L_*H_;                // 32
  int*   replist= (int*)(MZ + 32);                       // B*L
  int*   repcnt = replist + B_*L_;                       // 16

  enc_xg_kernel<<<B_*L_/16, 512, 0, stream>>>(src_tokens, emb, enc_Wih, enc_b, xg);
  enc_lstm_kernel<<<B_, 512, 0, stream>>>(xg, enc_Whh, enc_out);
  fuse_mid_kernel<<<B_, 512, 0, stream>>>(src_tokens, prev_tok, enc_out, copy_W, dstate,
                                          emb, dec_Wih, dec_b, attn_W, out_W, out_b, attn_out);
  copy_agg_kernel<<<B_, 256, 0, stream>>>(stw, enc_out, agg, replist, repcnt);
  gen_logits_kernel<<<(NV_+63)/64, 256, 0, stream>>>(attn_out, gen_W, oovc, total);
  copy_score2_kernel<<<dim3(B_,32), 128, 0, stream>>>(stw, agg, copy_W, attn_out, replist, repcnt, total);
  vocab_reduce_kernel<<<B_, 1024, 0, stream>>>(total, MZ);
  vocab_norm_kernel<<<dim3(B_,32), 256, 0, stream>>>(total, MZ);
}